// Round 1
// baseline (364.596 us; speedup 1.0000x reference)
//
#include <hip/hip_runtime.h>
#include <hip/hip_bf16.h>

#define ENT_D 256
#define REL_D 256
#define HIST_D 512
#define ACT_DD 512
#define IN_DD 1024
#define BB 512
#define AA 256

// ---------------------------------------------------------------------------
// K1: H = relu(X @ W1 + b1), X = [E(cur) | hist | R(qrel)] gathered on the fly
// grid (64, 2): 8 rows x 256 cols per block, 256 threads
// ---------------------------------------------------------------------------
__global__ __launch_bounds__(256) void mlp1_kernel(
    const int* __restrict__ cur, const int* __restrict__ qrel,
    const float* __restrict__ hist,
    const float* __restrict__ ent_emb, const float* __restrict__ rel_emb,
    const float* __restrict__ W1, const float* __restrict__ b1,
    float* __restrict__ H)
{
    __shared__ __align__(16) float Xs[8][IN_DD];   // 32 KB
    const int r0 = blockIdx.x * 8;
    const int j  = blockIdx.y * 256 + threadIdx.x;

    // gather-stage X tile: 8 rows x 1024 floats = 2048 float4 units
    for (int u = threadIdx.x; u < 8 * 256; u += 256) {
        int row = u >> 8;          // 0..7
        int c   = (u & 255) * 4;   // float col, multiple of 4
        float4 v;
        if (c < ENT_D) {
            v = *(const float4*)(ent_emb + (size_t)cur[r0 + row] * ENT_D + c);
        } else if (c < ENT_D + HIST_D) {
            v = *(const float4*)(hist + (size_t)(r0 + row) * HIST_D + (c - ENT_D));
        } else {
            v = *(const float4*)(rel_emb + (size_t)qrel[r0 + row] * REL_D + (c - ENT_D - HIST_D));
        }
        *(float4*)&Xs[row][c] = v;
    }
    __syncthreads();

    float acc[8];
    const float bj = b1[j];
#pragma unroll
    for (int r = 0; r < 8; ++r) acc[r] = bj;

    for (int k = 0; k < IN_DD; k += 4) {
        float w0 = W1[(size_t)(k + 0) * ACT_DD + j];
        float w1 = W1[(size_t)(k + 1) * ACT_DD + j];
        float w2 = W1[(size_t)(k + 2) * ACT_DD + j];
        float w3 = W1[(size_t)(k + 3) * ACT_DD + j];
#pragma unroll
        for (int r = 0; r < 8; ++r) {
            float4 x = *(const float4*)&Xs[r][k];
            acc[r] += x.x * w0 + x.y * w1 + x.z * w2 + x.w * w3;
        }
    }
#pragma unroll
    for (int r = 0; r < 8; ++r)
        H[(size_t)(r0 + r) * ACT_DD + j] = fmaxf(acc[r], 0.0f);
}

// ---------------------------------------------------------------------------
// K2: X2 = H @ W2 + b2  (H already relu'd). Same tiling, K=512.
// ---------------------------------------------------------------------------
__global__ __launch_bounds__(256) void mlp2_kernel(
    const float* __restrict__ H, const float* __restrict__ W2,
    const float* __restrict__ b2, float* __restrict__ X2)
{
    __shared__ __align__(16) float Hs[8][ACT_DD];  // 16 KB
    const int r0 = blockIdx.x * 8;
    const int j  = blockIdx.y * 256 + threadIdx.x;

    for (int u = threadIdx.x; u < 8 * 128; u += 256) {
        int row = u >> 7;
        int c   = (u & 127) * 4;
        *(float4*)&Hs[row][c] = *(const float4*)(H + (size_t)(r0 + row) * ACT_DD + c);
    }
    __syncthreads();

    float acc[8];
    const float bj = b2[j];
#pragma unroll
    for (int r = 0; r < 8; ++r) acc[r] = bj;

    for (int k = 0; k < ACT_DD; k += 4) {
        float w0 = W2[(size_t)(k + 0) * ACT_DD + j];
        float w1 = W2[(size_t)(k + 1) * ACT_DD + j];
        float w2 = W2[(size_t)(k + 2) * ACT_DD + j];
        float w3 = W2[(size_t)(k + 3) * ACT_DD + j];
#pragma unroll
        for (int r = 0; r < 8; ++r) {
            float4 x = *(const float4*)&Hs[r][k];
            acc[r] += x.x * w0 + x.y * w1 + x.z * w2 + x.w * w3;
        }
    }
#pragma unroll
    for (int r = 0; r < 8; ++r)
        X2[(size_t)(r0 + r) * ACT_DD + j] = acc[r];
}

// ---------------------------------------------------------------------------
// K3: scores = A_emb . X2 - (1-mask)*HUGE ; softmax ; entropy
// One block per batch row (512 blocks, 256 threads = 4 waves).
// One wave per action: 64 lanes split the 512-dim dot (coalesced float4).
// ---------------------------------------------------------------------------
__global__ __launch_bounds__(256) void score_kernel(
    const float* __restrict__ X2,
    const int* __restrict__ r_space, const int* __restrict__ e_space,
    const int* __restrict__ amask,
    const float* __restrict__ ent_emb, const float* __restrict__ rel_emb,
    float* __restrict__ dist, float* __restrict__ ent_out)
{
    __shared__ __align__(16) float x2s[ACT_DD];
    __shared__ float sc[AA];
    __shared__ float red[4];

    const int b   = blockIdx.x;
    const int tid = threadIdx.x;
    const int wave = tid >> 6;
    const int lane = tid & 63;

    x2s[tid]       = X2[(size_t)b * ACT_DD + tid];
    x2s[tid + 256] = X2[(size_t)b * ACT_DD + tid + 256];
    __syncthreads();

    // loop-invariant X2 fragments for this lane
    const float4 xr = ((const float4*)&x2s[0])[lane];       // rel part
    const float4 xe = ((const float4*)&x2s[REL_D])[lane];   // ent part

    for (int a = wave; a < AA; a += 4) {
        const int ir = r_space[b * AA + a];
        const int ie = e_space[b * AA + a];
        const float4 r4 = ((const float4*)(rel_emb + (size_t)ir * REL_D))[lane];
        const float4 e4 = ((const float4*)(ent_emb + (size_t)ie * ENT_D))[lane];
        float p = r4.x * xr.x + r4.y * xr.y + r4.z * xr.z + r4.w * xr.w
                + e4.x * xe.x + e4.y * xe.y + e4.z * xe.z + e4.w * xe.w;
#pragma unroll
        for (int off = 32; off > 0; off >>= 1) p += __shfl_xor(p, off, 64);
        if (lane == 0) {
            float m = (float)amask[b * AA + a];
            sc[a] = p - (1.0f - m) * 1e31f;
        }
    }
    __syncthreads();

    const float s = sc[tid];

    // block max
    float v = s;
#pragma unroll
    for (int off = 32; off > 0; off >>= 1) v = fmaxf(v, __shfl_xor(v, off, 64));
    if (lane == 0) red[wave] = v;
    __syncthreads();
    const float mx = fmaxf(fmaxf(red[0], red[1]), fmaxf(red[2], red[3]));
    __syncthreads();

    const float e = __expf(s - mx);

    // block sum of exp
    v = e;
#pragma unroll
    for (int off = 32; off > 0; off >>= 1) v += __shfl_xor(v, off, 64);
    if (lane == 0) red[wave] = v;
    __syncthreads();
    const float sum = red[0] + red[1] + red[2] + red[3];
    __syncthreads();

    const float p = e / sum;
    dist[(size_t)b * AA + tid] = p;

    // entropy = -sum p*log(p+eps)
    v = p * __logf(p + 1e-20f);
#pragma unroll
    for (int off = 32; off > 0; off >>= 1) v += __shfl_xor(v, off, 64);
    if (lane == 0) red[wave] = v;
    __syncthreads();
    if (tid == 0) ent_out[b] = -(red[0] + red[1] + red[2] + red[3]);
}

extern "C" void kernel_launch(void* const* d_in, const int* in_sizes, int n_in,
                              void* d_out, int out_size, void* d_ws, size_t ws_size,
                              hipStream_t stream) {
    const int*   cur      = (const int*)d_in[0];
    const int*   qrel     = (const int*)d_in[1];
    const float* hist     = (const float*)d_in[2];
    const int*   r_space  = (const int*)d_in[3];
    const int*   e_space  = (const int*)d_in[4];
    const int*   amask    = (const int*)d_in[5];
    const float* ent_emb  = (const float*)d_in[6];
    const float* rel_emb  = (const float*)d_in[7];
    const float* W1       = (const float*)d_in[8];
    const float* b1       = (const float*)d_in[9];
    const float* W2       = (const float*)d_in[10];
    const float* b2       = (const float*)d_in[11];

    float* out     = (float*)d_out;
    float* dist    = out;                         // [512, 256]
    float* entropy = out + (size_t)BB * AA;       // [512]

    float* H  = (float*)d_ws;                     // 512*512 fp32 = 1 MB
    float* X2 = H + (size_t)BB * ACT_DD;          // 512*512 fp32 = 1 MB

    mlp1_kernel<<<dim3(64, 2), 256, 0, stream>>>(cur, qrel, hist, ent_emb, rel_emb, W1, b1, H);
    mlp2_kernel<<<dim3(64, 2), 256, 0, stream>>>(H, W2, b2, X2);
    score_kernel<<<512, 256, 0, stream>>>(X2, r_space, e_space, amask, ent_emb, rel_emb, dist, entropy);
}

// Round 2
// 193.664 us; speedup vs baseline: 1.8826x; 1.8826x over previous
//
#include <hip/hip_runtime.h>
#include <hip/hip_bf16.h>

#define ENT_D 256
#define REL_D 256
#define HIST_D 512
#define ACT_DD 512
#define IN_DD 1024
#define BB 512
#define AA 256

typedef short bf16x8 __attribute__((ext_vector_type(8)));
typedef float floatx4 __attribute__((ext_vector_type(4)));

__device__ __forceinline__ unsigned short f2bf(float f) {
    unsigned u = __builtin_bit_cast(unsigned, f);
    return (unsigned short)((u + 0x7fffu + ((u >> 16) & 1u)) >> 16);  // RNE
}

// ---------------------------------------------------------------------------
// Fragment-major pack layouts (per 16x16x32 MFMA):
//  A-pack  [m_tile][k_tile][lane][8]:  val = A[m_tile*16 + (lane&15)][k_tile*32 + (lane>>4)*8 + j]
//  B-pack  [n_tile][k_tile][lane][8]:  val = B[k_tile*32 + (lane>>4)*8 + j][n_tile*16 + (lane&15)]
// GEMM fragment load = one coalesced b128 per wave per tile. No LDS in K-loop.
// ---------------------------------------------------------------------------

// Prep: one wave per pack tile.  Tiles: W1 (1024) | W2 (512) | X gathered (1024)
__global__ __launch_bounds__(256) void pack_kernel(
    const int* __restrict__ cur, const int* __restrict__ qrel,
    const float* __restrict__ hist,
    const float* __restrict__ ent_emb, const float* __restrict__ rel_emb,
    const float* __restrict__ W1, const float* __restrict__ W2,
    unsigned short* __restrict__ W1p, unsigned short* __restrict__ W2p,
    unsigned short* __restrict__ Xp)
{
    const int wid  = blockIdx.x * 4 + (threadIdx.x >> 6);
    const int lane = threadIdx.x & 63;
    const int l15  = lane & 15;
    const int quad = lane >> 4;
    unsigned short v[8];

    if (wid < 1024) {                      // W1: B-pack, K=1024, N=512
        const int t = wid, nt = t >> 5, kt = t & 31;
        const int n = nt * 16 + l15, k0 = kt * 32 + quad * 8;
#pragma unroll
        for (int j = 0; j < 8; ++j) v[j] = f2bf(W1[(size_t)(k0 + j) * ACT_DD + n]);
        *(bf16x8*)(W1p + ((size_t)t * 64 + lane) * 8) = *(bf16x8*)v;
    } else if (wid < 1536) {               // W2: B-pack, K=512, N=512
        const int t = wid - 1024, nt = t >> 4, kt = t & 15;
        const int n = nt * 16 + l15, k0 = kt * 32 + quad * 8;
#pragma unroll
        for (int j = 0; j < 8; ++j) v[j] = f2bf(W2[(size_t)(k0 + j) * ACT_DD + n]);
        *(bf16x8*)(W2p + ((size_t)t * 64 + lane) * 8) = *(bf16x8*)v;
    } else {                               // X = [E(cur)|hist|R(qrel)]: A-pack, M=512, K=1024
        const int t = wid - 1536, mt = t >> 5, kt = t & 31;
        const int m = mt * 16 + l15, k0 = kt * 32 + quad * 8;
        const float* src;
        if (k0 < ENT_D)            src = ent_emb + (size_t)cur[m] * ENT_D + k0;
        else if (k0 < ENT_D + HIST_D) src = hist + (size_t)m * HIST_D + (k0 - ENT_D);
        else                       src = rel_emb + (size_t)qrel[m] * REL_D + (k0 - ENT_D - HIST_D);
        float4 a = *(const float4*)src, b = *(const float4*)(src + 4);
        v[0]=f2bf(a.x); v[1]=f2bf(a.y); v[2]=f2bf(a.z); v[3]=f2bf(a.w);
        v[4]=f2bf(b.x); v[5]=f2bf(b.y); v[6]=f2bf(b.z); v[7]=f2bf(b.w);
        *(bf16x8*)(Xp + ((size_t)t * 64 + lane) * 8) = *(bf16x8*)v;
    }
}

// GEMM1: H = relu(X@W1 + b1) -> Hp in A-pack layout (bf16), via LDS repack.
// grid (32, 8): block = m_tile x 64 cols; wave nt = by*4+wave. K=1024 (32 k-tiles)
__global__ __launch_bounds__(256) void gemm1_kernel(
    const unsigned short* __restrict__ Xp, const unsigned short* __restrict__ W1p,
    const float* __restrict__ b1, unsigned short* __restrict__ Hp)
{
    __shared__ unsigned short sH[1024];    // 16 rows x 64 cols in A-pack order (2 tiles)
    const int mt = blockIdx.x, wave = threadIdx.x >> 6, lane = threadIdx.x & 63;
    const int nt = blockIdx.y * 4 + wave;

    const bf16x8* Av = (const bf16x8*)Xp  + (size_t)mt * 32 * 64 + lane;
    const bf16x8* Bv = (const bf16x8*)W1p + (size_t)nt * 32 * 64 + lane;
    floatx4 acc = {0.f, 0.f, 0.f, 0.f};
#pragma unroll 8
    for (int kt = 0; kt < 32; ++kt)
        acc = __builtin_amdgcn_mfma_f32_16x16x32_bf16(Av[kt * 64], Bv[kt * 64], acc, 0, 0, 0);

    const int col  = nt * 16 + (lane & 15);
    const float bj = b1[col];
    const int n_loc = wave * 16 + (lane & 15);          // 0..63 within block
    const int tile_loc = n_loc >> 5, quad2 = (n_loc & 31) >> 3, j2 = n_loc & 7;
#pragma unroll
    for (int reg = 0; reg < 4; ++reg) {
        const int row = (lane >> 4) * 4 + reg;          // m within tile, 0..15
        const float h = fmaxf(acc[reg] + bj, 0.f);
        sH[tile_loc * 512 + (row + 16 * quad2) * 8 + j2] = f2bf(h);
    }
    __syncthreads();
    // coalesced copy-out: Hp tiles (mt, by*2 + {0,1})
    const int h = threadIdx.x * 4;                      // halfword index
    const int tl = h >> 9, rest = h & 511;
    const size_t dst = ((size_t)(mt * 16 + blockIdx.y * 2 + tl) * 512 + rest);
    *(uint2*)(Hp + dst) = *(const uint2*)(sH + h);
}

// GEMM2: X2 = H@W2 + b2 (fp32 out, row-major). grid (32,8), K=512 (16 k-tiles)
__global__ __launch_bounds__(256) void gemm2_kernel(
    const unsigned short* __restrict__ Hp, const unsigned short* __restrict__ W2p,
    const float* __restrict__ b2, float* __restrict__ X2)
{
    const int mt = blockIdx.x, wave = threadIdx.x >> 6, lane = threadIdx.x & 63;
    const int nt = blockIdx.y * 4 + wave;

    const bf16x8* Av = (const bf16x8*)Hp  + (size_t)mt * 16 * 64 + lane;
    const bf16x8* Bv = (const bf16x8*)W2p + (size_t)nt * 16 * 64 + lane;
    floatx4 acc = {0.f, 0.f, 0.f, 0.f};
#pragma unroll
    for (int kt = 0; kt < 16; ++kt)
        acc = __builtin_amdgcn_mfma_f32_16x16x32_bf16(Av[kt * 64], Bv[kt * 64], acc, 0, 0, 0);

    const int col = nt * 16 + (lane & 15);
    const float bj = b2[col];
#pragma unroll
    for (int reg = 0; reg < 4; ++reg) {
        const int m = mt * 16 + (lane >> 4) * 4 + reg;
        X2[(size_t)m * ACT_DD + col] = acc[reg] + bj;
    }
}

// Scores: grid 2048 (4 blocks per batch row), 256 thr; each wave 16 actions,
// 4-wide ILP batches. Writes masked scores to ws.
__global__ __launch_bounds__(256) void score_kernel(
    const float* __restrict__ X2,
    const int* __restrict__ r_space, const int* __restrict__ e_space,
    const int* __restrict__ amask,
    const float* __restrict__ ent_emb, const float* __restrict__ rel_emb,
    float* __restrict__ scores)
{
    __shared__ __align__(16) float x2s[ACT_DD];
    const int b = blockIdx.x >> 2, chunk = blockIdx.x & 3;
    const int tid = threadIdx.x, wave = tid >> 6, lane = tid & 63;

    x2s[tid]       = X2[(size_t)b * ACT_DD + tid];
    x2s[tid + 256] = X2[(size_t)b * ACT_DD + tid + 256];
    __syncthreads();

    const float4 xr = ((const float4*)&x2s[0])[lane];
    const float4 xe = ((const float4*)&x2s[REL_D])[lane];
    const int a0 = chunk * 64 + wave * 16;

#pragma unroll
    for (int g = 0; g < 4; ++g) {
        const int ab = a0 + g * 4;
        int ir[4], ie[4];
        float p[4];
#pragma unroll
        for (int i = 0; i < 4; ++i) {
            ir[i] = r_space[b * AA + ab + i];
            ie[i] = e_space[b * AA + ab + i];
        }
#pragma unroll
        for (int i = 0; i < 4; ++i) {
            const float4 r4 = ((const float4*)(rel_emb + (size_t)ir[i] * REL_D))[lane];
            const float4 e4 = ((const float4*)(ent_emb + (size_t)ie[i] * ENT_D))[lane];
            p[i] = r4.x * xr.x + r4.y * xr.y + r4.z * xr.z + r4.w * xr.w
                 + e4.x * xe.x + e4.y * xe.y + e4.z * xe.z + e4.w * xe.w;
        }
#pragma unroll
        for (int off = 32; off > 0; off >>= 1) {
#pragma unroll
            for (int i = 0; i < 4; ++i) p[i] += __shfl_xor(p[i], off, 64);
        }
        if (lane == 0) {
#pragma unroll
            for (int i = 0; i < 4; ++i) {
                const float m = (float)amask[b * AA + ab + i];
                scores[(size_t)b * AA + ab + i] = p[i] - (1.0f - m) * 1e31f;
            }
        }
    }
}

// Softmax + entropy: 512 blocks x 256 thr
__global__ __launch_bounds__(256) void softmax_kernel(
    const float* __restrict__ scores, float* __restrict__ dist, float* __restrict__ ent_out)
{
    __shared__ float red[4];
    const int b = blockIdx.x, tid = threadIdx.x, wave = tid >> 6, lane = tid & 63;
    const float s = scores[(size_t)b * AA + tid];

    float v = s;
#pragma unroll
    for (int off = 32; off > 0; off >>= 1) v = fmaxf(v, __shfl_xor(v, off, 64));
    if (lane == 0) red[wave] = v;
    __syncthreads();
    const float mx = fmaxf(fmaxf(red[0], red[1]), fmaxf(red[2], red[3]));
    __syncthreads();

    const float e = __expf(s - mx);
    v = e;
#pragma unroll
    for (int off = 32; off > 0; off >>= 1) v += __shfl_xor(v, off, 64);
    if (lane == 0) red[wave] = v;
    __syncthreads();
    const float sum = red[0] + red[1] + red[2] + red[3];
    __syncthreads();

    const float p = e / sum;
    dist[(size_t)b * AA + tid] = p;

    v = p * __logf(p + 1e-20f);
#pragma unroll
    for (int off = 32; off > 0; off >>= 1) v += __shfl_xor(v, off, 64);
    if (lane == 0) red[wave] = v;
    __syncthreads();
    if (tid == 0) ent_out[b] = -(red[0] + red[1] + red[2] + red[3]);
}

extern "C" void kernel_launch(void* const* d_in, const int* in_sizes, int n_in,
                              void* d_out, int out_size, void* d_ws, size_t ws_size,
                              hipStream_t stream) {
    const int*   cur      = (const int*)d_in[0];
    const int*   qrel     = (const int*)d_in[1];
    const float* hist     = (const float*)d_in[2];
    const int*   r_space  = (const int*)d_in[3];
    const int*   e_space  = (const int*)d_in[4];
    const int*   amask    = (const int*)d_in[5];
    const float* ent_emb  = (const float*)d_in[6];
    const float* rel_emb  = (const float*)d_in[7];
    const float* W1       = (const float*)d_in[8];
    const float* b1       = (const float*)d_in[9];
    const float* W2       = (const float*)d_in[10];
    const float* b2       = (const float*)d_in[11];

    float* dist    = (float*)d_out;
    float* entropy = dist + (size_t)BB * AA;

    // ws layout (4 MB): W1p 1M | W2p 0.5M | Xp 1M (scores overlaid after gemm1) | Hp 0.5M | X2 1M
    char* w = (char*)d_ws;
    unsigned short* W1p = (unsigned short*)(w);
    unsigned short* W2p = (unsigned short*)(w + (1u << 20));
    unsigned short* Xp  = (unsigned short*)(w + (3u << 19));
    float*          scores = (float*)(w + (3u << 19));   // overlays Xp (dead after gemm1)
    unsigned short* Hp  = (unsigned short*)(w + (5u << 19));
    float*          X2  = (float*)(w + (6u << 19));

    pack_kernel<<<640, 256, 0, stream>>>(cur, qrel, hist, ent_emb, rel_emb, W1, W2, W1p, W2p, Xp);
    gemm1_kernel<<<dim3(32, 8), 256, 0, stream>>>(Xp, W1p, b1, Hp);
    gemm2_kernel<<<dim3(32, 8), 256, 0, stream>>>(Hp, W2p, b2, X2);
    score_kernel<<<2048, 256, 0, stream>>>(X2, r_space, e_space, amask, ent_emb, rel_emb, scores);
    softmax_kernel<<<512, 256, 0, stream>>>(scores, dist, entropy);
}

// Round 3
// 189.637 us; speedup vs baseline: 1.9226x; 1.0212x over previous
//
#include <hip/hip_runtime.h>
#include <hip/hip_bf16.h>

#define ENT_D 256
#define REL_D 256
#define HIST_D 512
#define ACT_DD 512
#define IN_DD 1024
#define BB 512
#define AA 256

typedef short bf16x8 __attribute__((ext_vector_type(8)));
typedef float floatx4 __attribute__((ext_vector_type(4)));

__device__ __forceinline__ unsigned short f2bf(float f) {
    unsigned u = __builtin_bit_cast(unsigned, f);
    return (unsigned short)((u + 0x7fffu + ((u >> 16) & 1u)) >> 16);  // RNE
}

// ---------------------------------------------------------------------------
// Fragment-major pack layouts (per 16x16x32 MFMA):
//  A-pack  [m_tile][k_tile][lane][8]:  val = A[m_tile*16 + (lane&15)][k_tile*32 + (lane>>4)*8 + j]
//  B-pack  [n_tile][k_tile][lane][8]:  val = B[k_tile*32 + (lane>>4)*8 + j][n_tile*16 + (lane&15)]
// ---------------------------------------------------------------------------

__global__ __launch_bounds__(256) void pack_kernel(
    const int* __restrict__ cur, const int* __restrict__ qrel,
    const float* __restrict__ hist,
    const float* __restrict__ ent_emb, const float* __restrict__ rel_emb,
    const float* __restrict__ W1, const float* __restrict__ W2,
    unsigned short* __restrict__ W1p, unsigned short* __restrict__ W2p,
    unsigned short* __restrict__ Xp)
{
    const int wid  = blockIdx.x * 4 + (threadIdx.x >> 6);
    const int lane = threadIdx.x & 63;
    const int l15  = lane & 15;
    const int quad = lane >> 4;
    unsigned short v[8];

    if (wid < 1024) {                      // W1: B-pack, K=1024, N=512
        const int t = wid, nt = t >> 5, kt = t & 31;
        const int n = nt * 16 + l15, k0 = kt * 32 + quad * 8;
#pragma unroll
        for (int j = 0; j < 8; ++j) v[j] = f2bf(W1[(size_t)(k0 + j) * ACT_DD + n]);
        *(bf16x8*)(W1p + ((size_t)t * 64 + lane) * 8) = *(bf16x8*)v;
    } else if (wid < 1536) {               // W2: B-pack, K=512, N=512
        const int t = wid - 1024, nt = t >> 4, kt = t & 15;
        const int n = nt * 16 + l15, k0 = kt * 32 + quad * 8;
#pragma unroll
        for (int j = 0; j < 8; ++j) v[j] = f2bf(W2[(size_t)(k0 + j) * ACT_DD + n]);
        *(bf16x8*)(W2p + ((size_t)t * 64 + lane) * 8) = *(bf16x8*)v;
    } else {                               // X = [E(cur)|hist|R(qrel)]: A-pack, M=512, K=1024
        const int t = wid - 1536, mt = t >> 5, kt = t & 31;
        const int m = mt * 16 + l15, k0 = kt * 32 + quad * 8;
        const float* src;
        if (k0 < ENT_D)            src = ent_emb + (size_t)cur[m] * ENT_D + k0;
        else if (k0 < ENT_D + HIST_D) src = hist + (size_t)m * HIST_D + (k0 - ENT_D);
        else                       src = rel_emb + (size_t)qrel[m] * REL_D + (k0 - ENT_D - HIST_D);
        float4 a = *(const float4*)src, b = *(const float4*)(src + 4);
        v[0]=f2bf(a.x); v[1]=f2bf(a.y); v[2]=f2bf(a.z); v[3]=f2bf(a.w);
        v[4]=f2bf(b.x); v[5]=f2bf(b.y); v[6]=f2bf(b.z); v[7]=f2bf(b.w);
        *(bf16x8*)(Xp + ((size_t)t * 64 + lane) * 8) = *(bf16x8*)v;
    }
}

// GEMM1: H = relu(X@W1 + b1) -> Hp in A-pack layout (bf16), via LDS repack.
__global__ __launch_bounds__(256) void gemm1_kernel(
    const unsigned short* __restrict__ Xp, const unsigned short* __restrict__ W1p,
    const float* __restrict__ b1, unsigned short* __restrict__ Hp)
{
    __shared__ unsigned short sH[1024];
    const int mt = blockIdx.x, wave = threadIdx.x >> 6, lane = threadIdx.x & 63;
    const int nt = blockIdx.y * 4 + wave;

    const bf16x8* Av = (const bf16x8*)Xp  + (size_t)mt * 32 * 64 + lane;
    const bf16x8* Bv = (const bf16x8*)W1p + (size_t)nt * 32 * 64 + lane;
    floatx4 acc = {0.f, 0.f, 0.f, 0.f};
#pragma unroll 8
    for (int kt = 0; kt < 32; ++kt)
        acc = __builtin_amdgcn_mfma_f32_16x16x32_bf16(Av[kt * 64], Bv[kt * 64], acc, 0, 0, 0);

    const int col  = nt * 16 + (lane & 15);
    const float bj = b1[col];
    const int n_loc = wave * 16 + (lane & 15);
    const int tile_loc = n_loc >> 5, quad2 = (n_loc & 31) >> 3, j2 = n_loc & 7;
#pragma unroll
    for (int reg = 0; reg < 4; ++reg) {
        const int row = (lane >> 4) * 4 + reg;
        const float h = fmaxf(acc[reg] + bj, 0.f);
        sH[tile_loc * 512 + (row + 16 * quad2) * 8 + j2] = f2bf(h);
    }
    __syncthreads();
    const int h = threadIdx.x * 4;
    const int tl = h >> 9, rest = h & 511;
    const size_t dst = ((size_t)(mt * 16 + blockIdx.y * 2 + tl) * 512 + rest);
    *(uint2*)(Hp + dst) = *(const uint2*)(sH + h);
}

// GEMM2: X2 = H@W2 + b2 (fp32 out, row-major).
__global__ __launch_bounds__(256) void gemm2_kernel(
    const unsigned short* __restrict__ Hp, const unsigned short* __restrict__ W2p,
    const float* __restrict__ b2, float* __restrict__ X2)
{
    const int mt = blockIdx.x, wave = threadIdx.x >> 6, lane = threadIdx.x & 63;
    const int nt = blockIdx.y * 4 + wave;

    const bf16x8* Av = (const bf16x8*)Hp  + (size_t)mt * 16 * 64 + lane;
    const bf16x8* Bv = (const bf16x8*)W2p + (size_t)nt * 16 * 64 + lane;
    floatx4 acc = {0.f, 0.f, 0.f, 0.f};
#pragma unroll
    for (int kt = 0; kt < 16; ++kt)
        acc = __builtin_amdgcn_mfma_f32_16x16x32_bf16(Av[kt * 64], Bv[kt * 64], acc, 0, 0, 0);

    const int col = nt * 16 + (lane & 15);
    const float bj = b2[col];
#pragma unroll
    for (int reg = 0; reg < 4; ++reg) {
        const int m = mt * 16 + (lane >> 4) * 4 + reg;
        X2[(size_t)m * ACT_DD + col] = acc[reg] + bj;
    }
}

// Fused scores + softmax + entropy. One block per batch row.
// 512 threads = 8 waves; each wave 32 actions in 4 groups of 8-wide ILP
// (explicit float4 arrays keep 16 gather loads in flight).
__global__ __launch_bounds__(512) void score_softmax_kernel(
    const float* __restrict__ X2,
    const int* __restrict__ r_space, const int* __restrict__ e_space,
    const int* __restrict__ amask,
    const float* __restrict__ ent_emb, const float* __restrict__ rel_emb,
    float* __restrict__ dist, float* __restrict__ ent_out)
{
    __shared__ __align__(16) float x2s[ACT_DD];
    __shared__ float sc[AA];
    __shared__ float red[8];

    const int b = blockIdx.x, tid = threadIdx.x;
    const int wave = tid >> 6, lane = tid & 63;

    x2s[tid] = X2[(size_t)b * ACT_DD + tid];
    __syncthreads();

    const float4 xr = ((const float4*)&x2s[0])[lane];       // rel half
    const float4 xe = ((const float4*)&x2s[REL_D])[lane];   // ent half

#pragma unroll
    for (int g = 0; g < 4; ++g) {
        const int ab = wave * 32 + g * 8;
        int ir[8], ie[8];
#pragma unroll
        for (int i = 0; i < 8; ++i) {
            ir[i] = r_space[b * AA + ab + i];
            ie[i] = e_space[b * AA + ab + i];
        }
        float4 r4[8], e4[8];
#pragma unroll
        for (int i = 0; i < 8; ++i)
            r4[i] = ((const float4*)(rel_emb + (size_t)ir[i] * REL_D))[lane];
#pragma unroll
        for (int i = 0; i < 8; ++i)
            e4[i] = ((const float4*)(ent_emb + (size_t)ie[i] * ENT_D))[lane];

        float p[8];
#pragma unroll
        for (int i = 0; i < 8; ++i)
            p[i] = r4[i].x * xr.x + r4[i].y * xr.y + r4[i].z * xr.z + r4[i].w * xr.w
                 + e4[i].x * xe.x + e4[i].y * xe.y + e4[i].z * xe.z + e4[i].w * xe.w;
#pragma unroll
        for (int off = 32; off > 0; off >>= 1) {
#pragma unroll
            for (int i = 0; i < 8; ++i) p[i] += __shfl_xor(p[i], off, 64);
        }
        if (lane == 0) {
#pragma unroll
            for (int i = 0; i < 8; ++i) sc[ab + i] = p[i];
        }
    }
    __syncthreads();

    // ---- softmax + entropy over the 256 scores (waves 0-3 carry data) ----
    float s = -3.0e38f;
    if (tid < AA) {
        const float m = (float)amask[b * AA + tid];   // coalesced
        s = sc[tid] - (1.0f - m) * 1e31f;
    }
    float v = s;
#pragma unroll
    for (int off = 32; off > 0; off >>= 1) v = fmaxf(v, __shfl_xor(v, off, 64));
    if (lane == 0) red[wave] = v;
    __syncthreads();
    float mx = red[0];
#pragma unroll
    for (int w = 1; w < 8; ++w) mx = fmaxf(mx, red[w]);
    __syncthreads();

    const float e = (tid < AA) ? __expf(s - mx) : 0.0f;
    v = e;
#pragma unroll
    for (int off = 32; off > 0; off >>= 1) v += __shfl_xor(v, off, 64);
    if (lane == 0) red[wave] = v;
    __syncthreads();
    float sum = red[0];
#pragma unroll
    for (int w = 1; w < 8; ++w) sum += red[w];
    __syncthreads();

    const float p = e / sum;
    if (tid < AA) dist[(size_t)b * AA + tid] = p;

    v = (tid < AA) ? p * __logf(p + 1e-20f) : 0.0f;
#pragma unroll
    for (int off = 32; off > 0; off >>= 1) v += __shfl_xor(v, off, 64);
    if (lane == 0) red[wave] = v;
    __syncthreads();
    if (tid == 0) {
        float t = red[0];
#pragma unroll
        for (int w = 1; w < 8; ++w) t += red[w];
        ent_out[b] = -t;
    }
}

extern "C" void kernel_launch(void* const* d_in, const int* in_sizes, int n_in,
                              void* d_out, int out_size, void* d_ws, size_t ws_size,
                              hipStream_t stream) {
    const int*   cur      = (const int*)d_in[0];
    const int*   qrel     = (const int*)d_in[1];
    const float* hist     = (const float*)d_in[2];
    const int*   r_space  = (const int*)d_in[3];
    const int*   e_space  = (const int*)d_in[4];
    const int*   amask    = (const int*)d_in[5];
    const float* ent_emb  = (const float*)d_in[6];
    const float* rel_emb  = (const float*)d_in[7];
    const float* W1       = (const float*)d_in[8];
    const float* b1       = (const float*)d_in[9];
    const float* W2       = (const float*)d_in[10];
    const float* b2       = (const float*)d_in[11];

    float* dist    = (float*)d_out;
    float* entropy = dist + (size_t)BB * AA;

    // ws layout: W1p 1M | W2p 0.5M | Xp 1M | Hp 0.5M | X2 1M
    char* w = (char*)d_ws;
    unsigned short* W1p = (unsigned short*)(w);
    unsigned short* W2p = (unsigned short*)(w + (1u << 20));
    unsigned short* Xp  = (unsigned short*)(w + (3u << 19));
    unsigned short* Hp  = (unsigned short*)(w + (5u << 19));
    float*          X2  = (float*)(w + (6u << 19));

    pack_kernel<<<640, 256, 0, stream>>>(cur, qrel, hist, ent_emb, rel_emb, W1, W2, W1p, W2p, Xp);
    gemm1_kernel<<<dim3(32, 8), 256, 0, stream>>>(Xp, W1p, b1, Hp);
    gemm2_kernel<<<dim3(32, 8), 256, 0, stream>>>(Hp, W2p, b2, X2);
    score_softmax_kernel<<<512, 512, 0, stream>>>(X2, r_space, e_space, amask,
                                                  ent_emb, rel_emb, dist, entropy);
}

// Round 4
// 184.759 us; speedup vs baseline: 1.9734x; 1.0264x over previous
//
#include <hip/hip_runtime.h>
#include <hip/hip_bf16.h>

#define ENT_D 256
#define REL_D 256
#define HIST_D 512
#define ACT_DD 512
#define IN_DD 1024
#define BB 512
#define AA 256

typedef short bf16x8 __attribute__((ext_vector_type(8)));
typedef float floatx4 __attribute__((ext_vector_type(4)));

__device__ __forceinline__ unsigned short f2bf(float f) {
    unsigned u = __builtin_bit_cast(unsigned, f);
    return (unsigned short)((u + 0x7fffu + ((u >> 16) & 1u)) >> 16);  // RNE
}

// ---------------------------------------------------------------------------
// Fragment-major pack layouts (per 16x16x32 MFMA):
//  A-pack  [m_tile][k_tile][lane][8]:  val = A[m_tile*16 + (lane&15)][k_tile*32 + (lane>>4)*8 + j]
//  B-pack  [n_tile][k_tile][lane][8]:  val = B[k_tile*32 + (lane>>4)*8 + j][n_tile*16 + (lane&15)]
// ---------------------------------------------------------------------------

__global__ __launch_bounds__(256) void pack_kernel(
    const int* __restrict__ cur, const int* __restrict__ qrel,
    const float* __restrict__ hist,
    const float* __restrict__ ent_emb, const float* __restrict__ rel_emb,
    const float* __restrict__ W1, const float* __restrict__ W2,
    unsigned short* __restrict__ W1p, unsigned short* __restrict__ W2p,
    unsigned short* __restrict__ Xp)
{
    const int wid  = blockIdx.x * 4 + (threadIdx.x >> 6);
    const int lane = threadIdx.x & 63;
    const int l15  = lane & 15;
    const int quad = lane >> 4;
    unsigned short v[8];

    if (wid < 1024) {                      // W1: B-pack, K=1024, N=512
        const int t = wid, nt = t >> 5, kt = t & 31;
        const int n = nt * 16 + l15, k0 = kt * 32 + quad * 8;
#pragma unroll
        for (int j = 0; j < 8; ++j) v[j] = f2bf(W1[(size_t)(k0 + j) * ACT_DD + n]);
        *(bf16x8*)(W1p + ((size_t)t * 64 + lane) * 8) = *(bf16x8*)v;
    } else if (wid < 1536) {               // W2: B-pack, K=512, N=512
        const int t = wid - 1024, nt = t >> 4, kt = t & 15;
        const int n = nt * 16 + l15, k0 = kt * 32 + quad * 8;
#pragma unroll
        for (int j = 0; j < 8; ++j) v[j] = f2bf(W2[(size_t)(k0 + j) * ACT_DD + n]);
        *(bf16x8*)(W2p + ((size_t)t * 64 + lane) * 8) = *(bf16x8*)v;
    } else {                               // X = [E(cur)|hist|R(qrel)]: A-pack, M=512, K=1024
        const int t = wid - 1536, mt = t >> 5, kt = t & 31;
        const int m = mt * 16 + l15, k0 = kt * 32 + quad * 8;
        const float* src;
        if (k0 < ENT_D)            src = ent_emb + (size_t)cur[m] * ENT_D + k0;
        else if (k0 < ENT_D + HIST_D) src = hist + (size_t)m * HIST_D + (k0 - ENT_D);
        else                       src = rel_emb + (size_t)qrel[m] * REL_D + (k0 - ENT_D - HIST_D);
        float4 a = *(const float4*)src, b = *(const float4*)(src + 4);
        v[0]=f2bf(a.x); v[1]=f2bf(a.y); v[2]=f2bf(a.z); v[3]=f2bf(a.w);
        v[4]=f2bf(b.x); v[5]=f2bf(b.y); v[6]=f2bf(b.z); v[7]=f2bf(b.w);
        *(bf16x8*)(Xp + ((size_t)t * 64 + lane) * 8) = *(bf16x8*)v;
    }
}

// GEMM1: H = relu(X@W1 + b1) -> Hp in A-pack layout (bf16), via LDS repack.
__global__ __launch_bounds__(256) void gemm1_kernel(
    const unsigned short* __restrict__ Xp, const unsigned short* __restrict__ W1p,
    const float* __restrict__ b1, unsigned short* __restrict__ Hp)
{
    __shared__ unsigned short sH[1024];
    const int mt = blockIdx.x, wave = threadIdx.x >> 6, lane = threadIdx.x & 63;
    const int nt = blockIdx.y * 4 + wave;

    const bf16x8* Av = (const bf16x8*)Xp  + (size_t)mt * 32 * 64 + lane;
    const bf16x8* Bv = (const bf16x8*)W1p + (size_t)nt * 32 * 64 + lane;
    floatx4 acc = {0.f, 0.f, 0.f, 0.f};
#pragma unroll 8
    for (int kt = 0; kt < 32; ++kt)
        acc = __builtin_amdgcn_mfma_f32_16x16x32_bf16(Av[kt * 64], Bv[kt * 64], acc, 0, 0, 0);

    const int col  = nt * 16 + (lane & 15);
    const float bj = b1[col];
    const int n_loc = wave * 16 + (lane & 15);
    const int tile_loc = n_loc >> 5, quad2 = (n_loc & 31) >> 3, j2 = n_loc & 7;
#pragma unroll
    for (int reg = 0; reg < 4; ++reg) {
        const int row = (lane >> 4) * 4 + reg;
        const float h = fmaxf(acc[reg] + bj, 0.f);
        sH[tile_loc * 512 + (row + 16 * quad2) * 8 + j2] = f2bf(h);
    }
    __syncthreads();
    const int h = threadIdx.x * 4;
    const int tl = h >> 9, rest = h & 511;
    const size_t dst = ((size_t)(mt * 16 + blockIdx.y * 2 + tl) * 512 + rest);
    *(uint2*)(Hp + dst) = *(const uint2*)(sH + h);
}

// GEMM2: X2 = H@W2 + b2 (fp32 out, row-major).
__global__ __launch_bounds__(256) void gemm2_kernel(
    const unsigned short* __restrict__ Hp, const unsigned short* __restrict__ W2p,
    const float* __restrict__ b2, float* __restrict__ X2)
{
    const int mt = blockIdx.x, wave = threadIdx.x >> 6, lane = threadIdx.x & 63;
    const int nt = blockIdx.y * 4 + wave;

    const bf16x8* Av = (const bf16x8*)Hp  + (size_t)mt * 16 * 64 + lane;
    const bf16x8* Bv = (const bf16x8*)W2p + (size_t)nt * 16 * 64 + lane;
    floatx4 acc = {0.f, 0.f, 0.f, 0.f};
#pragma unroll
    for (int kt = 0; kt < 16; ++kt)
        acc = __builtin_amdgcn_mfma_f32_16x16x32_bf16(Av[kt * 64], Bv[kt * 64], acc, 0, 0, 0);

    const int col = nt * 16 + (lane & 15);
    const float bj = b2[col];
#pragma unroll
    for (int reg = 0; reg < 4; ++reg) {
        const int m = mt * 16 + (lane >> 4) * 4 + reg;
        X2[(size_t)m * ACT_DD + col] = acc[reg] + bj;
    }
}

// Fused scores + softmax + entropy with MASK-SKIP.
// One block per batch row; 512 threads = 8 waves.
// Masked actions (≈50%) produce exactly p=0 / zero entropy contribution in the
// reference (exp(-1e31-mx)==0.0f), so we never gather their embeddings.
// Unmasked action ids are compacted into an LDS list (ballot/popc), padded to
// a multiple of 64 with duplicates of list[0] (benign same-value sc writes),
// then processed 8 actions per wave per pass (8-wide ILP, branch-free).
__global__ __launch_bounds__(512) void score_softmax_kernel(
    const float* __restrict__ X2,
    const int* __restrict__ r_space, const int* __restrict__ e_space,
    const int* __restrict__ amask,
    const float* __restrict__ ent_emb, const float* __restrict__ rel_emb,
    float* __restrict__ dist, float* __restrict__ ent_out)
{
    __shared__ __align__(16) float x2s[ACT_DD];
    __shared__ float sc[AA];
    __shared__ int   list[AA];
    __shared__ int   wcnt[4];
    __shared__ int   n_u_s;
    __shared__ float red[8];

    const int b = blockIdx.x, tid = threadIdx.x;
    const int wave = tid >> 6, lane = tid & 63;

    x2s[tid] = X2[(size_t)b * ACT_DD + tid];

    // ---- compaction of unmasked action ids (waves 0-3 carry tid<256) ----
    int m = 0;
    unsigned long long bal = 0;
    int pre = 0;
    if (tid < AA) {
        m = amask[b * AA + tid];
        sc[tid] = 0.0f;
    }
    if (wave < 4) {
        bal = __ballot(m != 0);
        pre = __popcll(bal & ((1ull << lane) - 1ull));
        if (lane == 0) wcnt[wave] = __popcll(bal);
    }
    __syncthreads();

    if (wave < 4) {
        int off = 0;
#pragma unroll
        for (int w = 0; w < 4; ++w) if (w < wave) off += wcnt[w];
        if (m != 0) list[off + pre] = tid;
        if (tid == 0) n_u_s = wcnt[0] + wcnt[1] + wcnt[2] + wcnt[3];
    }
    __syncthreads();

    const int n_u = n_u_s;
    const int padded = (n_u + 63) & ~63;
    if (tid < padded - n_u) list[n_u + tid] = list[0];
    __syncthreads();

    const float4 xr = ((const float4*)&x2s[0])[lane];       // rel half
    const float4 xe = ((const float4*)&x2s[REL_D])[lane];   // ent half

    for (int base = wave * 8; base < padded; base += 64) {
        int ai[8], ir[8], ie[8];
#pragma unroll
        for (int i = 0; i < 8; ++i) ai[i] = list[base + i];
#pragma unroll
        for (int i = 0; i < 8; ++i) {
            ir[i] = r_space[b * AA + ai[i]];
            ie[i] = e_space[b * AA + ai[i]];
        }
        float4 r4[8], e4[8];
#pragma unroll
        for (int i = 0; i < 8; ++i)
            r4[i] = ((const float4*)(rel_emb + (size_t)ir[i] * REL_D))[lane];
#pragma unroll
        for (int i = 0; i < 8; ++i)
            e4[i] = ((const float4*)(ent_emb + (size_t)ie[i] * ENT_D))[lane];

        float p[8];
#pragma unroll
        for (int i = 0; i < 8; ++i)
            p[i] = r4[i].x * xr.x + r4[i].y * xr.y + r4[i].z * xr.z + r4[i].w * xr.w
                 + e4[i].x * xe.x + e4[i].y * xe.y + e4[i].z * xe.z + e4[i].w * xe.w;
#pragma unroll
        for (int off = 32; off > 0; off >>= 1) {
#pragma unroll
            for (int i = 0; i < 8; ++i) p[i] += __shfl_xor(p[i], off, 64);
        }
        if (lane == 0) {
#pragma unroll
            for (int i = 0; i < 8; ++i) sc[ai[i]] = p[i];
        }
    }
    __syncthreads();

    // ---- softmax + entropy over 256 scores ----
    float s = -3.0e38f;
    if (tid < AA) s = (m != 0) ? sc[tid] : (sc[tid] - 1e31f);  // sc=0 for masked
    float v = s;
#pragma unroll
    for (int off = 32; off > 0; off >>= 1) v = fmaxf(v, __shfl_xor(v, off, 64));
    if (lane == 0) red[wave] = v;
    __syncthreads();
    float mx = red[0];
#pragma unroll
    for (int w = 1; w < 8; ++w) mx = fmaxf(mx, red[w]);
    __syncthreads();

    const float e = (tid < AA) ? __expf(s - mx) : 0.0f;
    v = e;
#pragma unroll
    for (int off = 32; off > 0; off >>= 1) v += __shfl_xor(v, off, 64);
    if (lane == 0) red[wave] = v;
    __syncthreads();
    float sum = red[0];
#pragma unroll
    for (int w = 1; w < 8; ++w) sum += red[w];
    __syncthreads();

    const float p = e / sum;
    if (tid < AA) dist[(size_t)b * AA + tid] = p;

    v = (tid < AA) ? p * __logf(p + 1e-20f) : 0.0f;
#pragma unroll
    for (int off = 32; off > 0; off >>= 1) v += __shfl_xor(v, off, 64);
    if (lane == 0) red[wave] = v;
    __syncthreads();
    if (tid == 0) {
        float t = red[0];
#pragma unroll
        for (int w = 1; w < 8; ++w) t += red[w];
        ent_out[b] = -t;
    }
}

extern "C" void kernel_launch(void* const* d_in, const int* in_sizes, int n_in,
                              void* d_out, int out_size, void* d_ws, size_t ws_size,
                              hipStream_t stream) {
    const int*   cur      = (const int*)d_in[0];
    const int*   qrel     = (const int*)d_in[1];
    const float* hist     = (const float*)d_in[2];
    const int*   r_space  = (const int*)d_in[3];
    const int*   e_space  = (const int*)d_in[4];
    const int*   amask    = (const int*)d_in[5];
    const float* ent_emb  = (const float*)d_in[6];
    const float* rel_emb  = (const float*)d_in[7];
    const float* W1       = (const float*)d_in[8];
    const float* b1       = (const float*)d_in[9];
    const float* W2       = (const float*)d_in[10];
    const float* b2       = (const float*)d_in[11];

    float* dist    = (float*)d_out;
    float* entropy = dist + (size_t)BB * AA;

    // ws layout: W1p 1M | W2p 0.5M | Xp 1M | Hp 0.5M | X2 1M
    char* w = (char*)d_ws;
    unsigned short* W1p = (unsigned short*)(w);
    unsigned short* W2p = (unsigned short*)(w + (1u << 20));
    unsigned short* Xp  = (unsigned short*)(w + (3u << 19));
    unsigned short* Hp  = (unsigned short*)(w + (5u << 19));
    float*          X2  = (float*)(w + (6u << 19));

    pack_kernel<<<640, 256, 0, stream>>>(cur, qrel, hist, ent_emb, rel_emb, W1, W2, W1p, W2p, Xp);
    gemm1_kernel<<<dim3(32, 8), 256, 0, stream>>>(Xp, W1p, b1, Hp);
    gemm2_kernel<<<dim3(32, 8), 256, 0, stream>>>(Hp, W2p, b2, X2);
    score_softmax_kernel<<<512, 512, 0, stream>>>(X2, r_space, e_space, amask,
                                                  ent_emb, rel_emb, dist, entropy);
}